// Round 1
// baseline (3296.177 us; speedup 1.0000x reference)
//
#include <hip/hip_runtime.h>

// Problem constants (match reference)
#define G_  4
#define N_  100000
#define E_  500000
#define B_  512
#define V_  50000
#define D_  300
#define H_  128
#define C_  20
#define NH_ 3

__device__ __forceinline__ int lower_bound_i(const int* __restrict__ a, int n, int v) {
    int lo = 0, hi = n;
    while (lo < hi) {
        int mid = (lo + hi) >> 1;
        if (a[mid] < v) lo = mid + 1; else hi = mid;
    }
    return lo;
}

// ---------------------------------------------------------------------------
// Projection: h[n][c] = sum_d emb[idx[n]][d] * Wp[d][c] + bp[c]
// Tiled fp32 GEMM: BM=64 (nodes), BN=128 (all H), BK=60 (300 = 5*60).
// Writes the result to BOTH hA and hB (hB serves as the init for step-1 scatter).
// ---------------------------------------------------------------------------
__global__ __launch_bounds__(256) void proj_kernel(
    const int* __restrict__ idx, const float* __restrict__ emb,
    const float* __restrict__ Wp, const float* __restrict__ bp,
    float* __restrict__ hA, float* __restrict__ hB)
{
    __shared__ __align__(16) float As[64][60];
    __shared__ __align__(16) float Bs[60][128];

    const int tid  = threadIdx.x;
    const int row0 = blockIdx.x * 64;
    const int tm   = tid >> 4;   // 0..15 -> 4 rows each
    const int tn   = tid & 15;   // 0..15 -> 8 cols each

    float acc[4][8];
#pragma unroll
    for (int i = 0; i < 4; ++i)
#pragma unroll
        for (int j = 0; j < 8; ++j) acc[i][j] = 0.f;

    const int kl   = tid & 63;   // lane within row-load
    const int mrow = tid >> 6;   // 0..3

    for (int k0 = 0; k0 < D_; k0 += 60) {
        // Load A tile (gathered embedding rows), 4 rows per pass x 16 passes
        if (kl < 60) {
#pragma unroll
            for (int mb = 0; mb < 16; ++mb) {
                int m = mb * 4 + mrow;
                int n = row0 + m;
                float v = 0.f;
                if (n < N_) v = emb[(long)idx[n] * D_ + k0 + kl];
                As[m][kl] = v;
            }
        }
        // Load B tile (W_proj slice), fully coalesced
#pragma unroll
        for (int i = 0; i < 30; ++i) {
            int flat = tid + i * 256;
            int k = flat >> 7, n = flat & 127;
            Bs[k][n] = Wp[(k0 + k) * H_ + n];
        }
        __syncthreads();

#pragma unroll 4
        for (int k = 0; k < 60; ++k) {
            float a0 = As[tm * 4 + 0][k];
            float a1 = As[tm * 4 + 1][k];
            float a2 = As[tm * 4 + 2][k];
            float a3 = As[tm * 4 + 3][k];
            float4 b0 = *reinterpret_cast<const float4*>(&Bs[k][tn * 8]);
            float4 b1 = *reinterpret_cast<const float4*>(&Bs[k][tn * 8 + 4]);
            float bb[8] = {b0.x, b0.y, b0.z, b0.w, b1.x, b1.y, b1.z, b1.w};
#pragma unroll
            for (int j = 0; j < 8; ++j) {
                acc[0][j] += a0 * bb[j];
                acc[1][j] += a1 * bb[j];
                acc[2][j] += a2 * bb[j];
                acc[3][j] += a3 * bb[j];
            }
        }
        __syncthreads();
    }

#pragma unroll
    for (int i = 0; i < 4; ++i) {
        int n = row0 + tm * 4 + i;
        if (n < N_) {
#pragma unroll
            for (int j = 0; j < 8; ++j) {
                int col = tn * 8 + j;
                float v = acc[i][j] + bp[col];
                hA[(long)n * H_ + col] = v;
                hB[(long)n * H_ + col] = v;
            }
        }
    }
}

// ---------------------------------------------------------------------------
// In-degree count (atomic), then invert in-place: deg -> inv_deg
// ---------------------------------------------------------------------------
__global__ __launch_bounds__(256) void deg_kernel(const int* __restrict__ dst,
                                                  float* __restrict__ deg, int E)
{
    int e = blockIdx.x * 256 + threadIdx.x;
    if (e < E) atomicAdd(&deg[dst[e]], 1.0f);
}

__global__ __launch_bounds__(256) void invdeg_kernel(float* __restrict__ deg, int n)
{
    int i = blockIdx.x * 256 + threadIdx.x;
    if (i < n) {
        float d = deg[i];
        deg[i] = d > 0.f ? 1.0f / d : 0.f;
    }
}

// ---------------------------------------------------------------------------
// One propagation step: h_new[dst] += inv_deg[dst] * relu(ep*ew[e]) * h_old[src]
// h_new must be pre-initialized to h_old (we fold "h + agg" into the scatter).
// 2 edges per 256-thread block; thread = one H column of one edge.
// ---------------------------------------------------------------------------
__global__ __launch_bounds__(256) void prop_kernel(
    const int* __restrict__ src, const int* __restrict__ dst,
    const float* __restrict__ ew, const float* __restrict__ ep,
    const float* __restrict__ invdeg,
    const float* __restrict__ h_old, float* __restrict__ h_new, int E)
{
    int e   = blockIdx.x * 2 + (threadIdx.x >> 7);
    int col = threadIdx.x & 127;
    if (e >= E) return;
    int s = src[e], d = dst[e];
    float w = ep[0] * ew[e];
    w = w > 0.f ? w : 0.f;
    float coef = w * invdeg[d];
    if (coef != 0.f) {
        float v = h_old[(long)s * H_ + col] * coef;
        atomicAdd(&h_new[(long)d * H_ + col], v);
    }
}

// ---------------------------------------------------------------------------
// Doc pooling (mean over sorted node_graph_ids via binary search) + ReLU +
// classifier: logits[b][c] = relu(doc) @ Wc + bc. One block per doc.
// ---------------------------------------------------------------------------
__global__ __launch_bounds__(128) void doc_cls_kernel(
    const int* __restrict__ gid, const float* __restrict__ h,
    const float* __restrict__ Wc, const float* __restrict__ bc,
    float* __restrict__ logits)
{
    const int b   = blockIdx.x;
    const int tid = threadIdx.x;

    int lo = lower_bound_i(gid, N_, b);
    int hi = lower_bound_i(gid, N_, b + 1);

    float s = 0.f;
    for (int n = lo; n < hi; ++n) s += h[(long)n * H_ + tid];

    float cnt = (float)(hi - lo);
    float doc = s / fmaxf(cnt, 1.0f);

    __shared__ float sdoc[H_];
    sdoc[tid] = fmaxf(doc, 0.f);
    __syncthreads();

    if (tid < C_) {
        float acc = bc[tid];
#pragma unroll 8
        for (int hh = 0; hh < H_; ++hh) acc += sdoc[hh] * Wc[hh * C_ + tid];
        logits[b * C_ + tid] = acc;
    }
}

// ---------------------------------------------------------------------------
// Head fusion (Conv1d over G as einsum) + mean over heads + softmax.
// One block per doc. Writes predictions [0:B*C) then fused_logits [B*C:2*B*C).
// ---------------------------------------------------------------------------
__global__ __launch_bounds__(64) void fuse_kernel(
    const float* __restrict__ logits,  // [G][B][C]
    const float* __restrict__ Wf,      // [NH][C][C][G]
    const float* __restrict__ bf,      // [NH][C]
    float* __restrict__ out)
{
    const int b   = blockIdx.x;
    const int tid = threadIdx.x;

    __shared__ float s[C_ * G_];   // s[i*G + g]
    __shared__ float fl[C_];

    for (int t = tid; t < C_ * G_; t += 64) {
        int i = t >> 2, g = t & 3;
        s[t] = logits[((long)g * B_ + b) * C_ + i];
    }
    __syncthreads();

    if (tid < C_) {
        float acc = 0.f;
        for (int hd = 0; hd < NH_; ++hd) {
            float a = bf[hd * C_ + tid];
            const float* wrow = &Wf[((hd * C_ + tid) * C_) * G_];
#pragma unroll 5
            for (int i = 0; i < C_; ++i) {
#pragma unroll
                for (int g = 0; g < G_; ++g)
                    a += s[i * G_ + g] * wrow[i * G_ + g];
            }
            acc += a;
        }
        fl[tid] = acc * (1.0f / 3.0f);
    }
    __syncthreads();

    if (tid < C_) {
        float f = fl[tid];
        float m = -1e30f;
#pragma unroll
        for (int i = 0; i < C_; ++i) m = fmaxf(m, fl[i]);
        float ssum = 0.f;
#pragma unroll
        for (int i = 0; i < C_; ++i) ssum += expf(fl[i] - m);
        out[b * C_ + tid] = expf(f - m) / ssum;
        out[B_ * C_ + b * C_ + tid] = f;
    }
}

// ---------------------------------------------------------------------------
extern "C" void kernel_launch(void* const* d_in, const int* in_sizes, int n_in,
                              void* d_out, int out_size, void* d_ws, size_t ws_size,
                              hipStream_t stream)
{
    const int*   node_indices = (const int*)d_in[0];
    const int*   srcA         = (const int*)d_in[1];
    const int*   dstA         = (const int*)d_in[2];
    const int*   gidA         = (const int*)d_in[3];
    const float* ewA          = (const float*)d_in[4];
    const float* emb          = (const float*)d_in[5];
    const float* ep           = (const float*)d_in[6];
    const float* Wp           = (const float*)d_in[7];
    const float* bp           = (const float*)d_in[8];
    const float* Wc           = (const float*)d_in[9];
    const float* bc           = (const float*)d_in[10];
    const float* Wf           = (const float*)d_in[11];
    const float* bf           = (const float*)d_in[12];
    float*       out          = (float*)d_out;

    // Workspace layout (fp32): hA [N*H] | hB [N*H] | deg [N] | logits [G*B*C]
    float* hA     = (float*)d_ws;
    float* hB     = hA + (size_t)N_ * H_;
    float* deg    = hB + (size_t)N_ * H_;
    float* logits = deg + N_;
    // total ~103 MB

    for (int g = 0; g < G_; ++g) {
        const int*   idx = node_indices + (size_t)g * N_;
        const int*   src = srcA + (size_t)g * E_;
        const int*   dst = dstA + (size_t)g * E_;
        const int*   gid = gidA + (size_t)g * N_;
        const float* ew  = ewA + (size_t)g * E_;

        proj_kernel<<<(N_ + 63) / 64, 256, 0, stream>>>(
            idx, emb, Wp + (size_t)g * D_ * H_, bp + (size_t)g * H_, hA, hB);

        hipMemsetAsync(deg, 0, N_ * sizeof(float), stream);
        deg_kernel<<<(E_ + 255) / 256, 256, 0, stream>>>(dst, deg, E_);
        invdeg_kernel<<<(N_ + 255) / 256, 256, 0, stream>>>(deg, N_);

        // step 1: read hA, accumulate into hB (hB already == hA from proj)
        prop_kernel<<<E_ / 2, 256, 0, stream>>>(src, dst, ew, ep + g, deg, hA, hB, E_);

        // step 2: init hA := hB, then read hB, accumulate into hA
        hipMemcpyAsync(hA, hB, (size_t)N_ * H_ * sizeof(float),
                       hipMemcpyDeviceToDevice, stream);
        prop_kernel<<<E_ / 2, 256, 0, stream>>>(src, dst, ew, ep + g, deg, hB, hA, E_);

        doc_cls_kernel<<<B_, 128, 0, stream>>>(
            gid, hA, Wc + (size_t)g * H_ * C_, bc + (size_t)g * C_,
            logits + (size_t)g * B_ * C_);
    }

    fuse_kernel<<<B_, 64, 0, stream>>>(logits, Wf, bf, out);
}

// Round 2
// 2431.781 us; speedup vs baseline: 1.3555x; 1.3555x over previous
//
#include <hip/hip_runtime.h>

// Problem constants (match reference)
#define G_  4
#define N_  100000
#define E_  500000
#define B_  512
#define V_  50000
#define D_  300
#define H_  128
#define C_  20
#define NH_ 3

__device__ __forceinline__ int lower_bound_i(const int* __restrict__ a, int n, int v) {
    int lo = 0, hi = n;
    while (lo < hi) {
        int mid = (lo + hi) >> 1;
        if (a[mid] < v) lo = mid + 1; else hi = mid;
    }
    return lo;
}

// ---------------------------------------------------------------------------
// Projection: h[n][c] = sum_d emb[idx[n]][d] * Wp[d][c] + bp[c]
// Tiled fp32 GEMM: BM=64 (nodes), BN=128 (all H), BK=60 (300 = 5*60).
// ---------------------------------------------------------------------------
__global__ __launch_bounds__(256) void proj_kernel(
    const int* __restrict__ idx, const float* __restrict__ emb,
    const float* __restrict__ Wp, const float* __restrict__ bp,
    float* __restrict__ hA)
{
    __shared__ __align__(16) float As[64][60];
    __shared__ __align__(16) float Bs[60][128];

    const int tid  = threadIdx.x;
    const int row0 = blockIdx.x * 64;
    const int tm   = tid >> 4;   // 0..15 -> 4 rows each
    const int tn   = tid & 15;   // 0..15 -> 8 cols each

    float acc[4][8];
#pragma unroll
    for (int i = 0; i < 4; ++i)
#pragma unroll
        for (int j = 0; j < 8; ++j) acc[i][j] = 0.f;

    const int kl   = tid & 63;   // lane within row-load
    const int mrow = tid >> 6;   // 0..3

    for (int k0 = 0; k0 < D_; k0 += 60) {
        if (kl < 60) {
#pragma unroll
            for (int mb = 0; mb < 16; ++mb) {
                int m = mb * 4 + mrow;
                int n = row0 + m;
                float v = 0.f;
                if (n < N_) v = emb[(long)idx[n] * D_ + k0 + kl];
                As[m][kl] = v;
            }
        }
#pragma unroll
        for (int i = 0; i < 30; ++i) {
            int flat = tid + i * 256;
            int k = flat >> 7, n = flat & 127;
            Bs[k][n] = Wp[(k0 + k) * H_ + n];
        }
        __syncthreads();

#pragma unroll 4
        for (int k = 0; k < 60; ++k) {
            float a0 = As[tm * 4 + 0][k];
            float a1 = As[tm * 4 + 1][k];
            float a2 = As[tm * 4 + 2][k];
            float a3 = As[tm * 4 + 3][k];
            float4 b0 = *reinterpret_cast<const float4*>(&Bs[k][tn * 8]);
            float4 b1 = *reinterpret_cast<const float4*>(&Bs[k][tn * 8 + 4]);
            float bb[8] = {b0.x, b0.y, b0.z, b0.w, b1.x, b1.y, b1.z, b1.w};
#pragma unroll
            for (int j = 0; j < 8; ++j) {
                acc[0][j] += a0 * bb[j];
                acc[1][j] += a1 * bb[j];
                acc[2][j] += a2 * bb[j];
                acc[3][j] += a3 * bb[j];
            }
        }
        __syncthreads();
    }

#pragma unroll
    for (int i = 0; i < 4; ++i) {
        int n = row0 + tm * 4 + i;
        if (n < N_) {
#pragma unroll
            for (int j = 0; j < 8; ++j) {
                int col = tn * 8 + j;
                hA[(long)n * H_ + col] = acc[i][j] + bp[col];
            }
        }
    }
}

// ---------------------------------------------------------------------------
// CSR build: in-degree count -> exclusive scan -> scatter (src, coef) by dst
// ---------------------------------------------------------------------------
__global__ __launch_bounds__(256) void deg_count_kernel(const int* __restrict__ dst,
                                                        int* __restrict__ deg, int E)
{
    int e = blockIdx.x * 256 + threadIdx.x;
    if (e < E) atomicAdd(&deg[dst[e]], 1);
}

// Single-block exclusive scan of deg[N] -> off[N+1]
__global__ __launch_bounds__(1024) void scan_kernel(const int* __restrict__ deg,
                                                    int* __restrict__ off)
{
    __shared__ int part[1024];
    const int CH = (N_ + 1023) / 1024;   // 98 elements per thread
    const int t = threadIdx.x;
    const int begin = t * CH;
    const int end   = min(begin + CH, N_);

    int s = 0;
    for (int i = begin; i < end; ++i) s += deg[i];
    part[t] = s;
    __syncthreads();

    for (int ofs = 1; ofs < 1024; ofs <<= 1) {
        int v = 0;
        if (t >= ofs) v = part[t - ofs];
        __syncthreads();
        if (t >= ofs) part[t] += v;
        __syncthreads();
    }

    int run = (t > 0) ? part[t - 1] : 0;  // exclusive prefix for this chunk
    for (int i = begin; i < end; ++i) { off[i] = run; run += deg[i]; }
    if (t == 1023) off[N_] = part[1023];
}

__global__ __launch_bounds__(256) void scatter_kernel(
    const int* __restrict__ src, const int* __restrict__ dst,
    const float* __restrict__ ew, const float* __restrict__ ep,
    const int* __restrict__ off, int* __restrict__ cnt,
    int* __restrict__ csr_src, float* __restrict__ csr_coef, int E)
{
    int e = blockIdx.x * 256 + threadIdx.x;
    if (e >= E) return;
    int d = dst[e];
    int pos = off[d] + atomicAdd(&cnt[d], 1);
    csr_src[pos] = src[e];
    float w = ep[0] * ew[e];
    csr_coef[pos] = fmaxf(w, 0.f);
}

// ---------------------------------------------------------------------------
// Gather-based propagation step (no atomics):
//   h_new[n] = h_old[n] + inv_deg[n] * sum_{e in CSR[n]} coef[e] * h_old[src[e]]
// One wave (64 lanes) per node; each lane owns 2 of the 128 columns (float2).
// ---------------------------------------------------------------------------
__global__ __launch_bounds__(256) void prop_gather_kernel(
    const int* __restrict__ off, const int* __restrict__ csr_src,
    const float* __restrict__ csr_coef,
    const float* __restrict__ h_old, float* __restrict__ h_new)
{
    const int n = blockIdx.x * 4 + (threadIdx.x >> 6);
    if (n >= N_) return;
    const int lane = threadIdx.x & 63;

    const int lo = off[n], hi = off[n + 1];
    float2 acc = make_float2(0.f, 0.f);
    for (int i = lo; i < hi; ++i) {
        const int s   = csr_src[i];
        const float c = csr_coef[i];
        const float2 v = *reinterpret_cast<const float2*>(&h_old[(size_t)s * H_ + lane * 2]);
        acc.x += c * v.x;
        acc.y += c * v.y;
    }
    const float inv = (hi > lo) ? 1.0f / (float)(hi - lo) : 0.f;
    const float2 hv = *reinterpret_cast<const float2*>(&h_old[(size_t)n * H_ + lane * 2]);
    float2 o = make_float2(hv.x + inv * acc.x, hv.y + inv * acc.y);
    *reinterpret_cast<float2*>(&h_new[(size_t)n * H_ + lane * 2]) = o;
}

// ---------------------------------------------------------------------------
// Doc pooling (mean over sorted node_graph_ids via binary search) + ReLU +
// classifier: logits[b][c] = relu(doc) @ Wc + bc. One block per doc.
// ---------------------------------------------------------------------------
__global__ __launch_bounds__(128) void doc_cls_kernel(
    const int* __restrict__ gid, const float* __restrict__ h,
    const float* __restrict__ Wc, const float* __restrict__ bc,
    float* __restrict__ logits)
{
    const int b   = blockIdx.x;
    const int tid = threadIdx.x;

    int lo = lower_bound_i(gid, N_, b);
    int hi = lower_bound_i(gid, N_, b + 1);

    float s = 0.f;
    for (int n = lo; n < hi; ++n) s += h[(long)n * H_ + tid];

    float cnt = (float)(hi - lo);
    float doc = s / fmaxf(cnt, 1.0f);

    __shared__ float sdoc[H_];
    sdoc[tid] = fmaxf(doc, 0.f);
    __syncthreads();

    if (tid < C_) {
        float acc = bc[tid];
#pragma unroll 8
        for (int hh = 0; hh < H_; ++hh) acc += sdoc[hh] * Wc[hh * C_ + tid];
        logits[b * C_ + tid] = acc;
    }
}

// ---------------------------------------------------------------------------
// Head fusion (Conv1d over G as einsum) + mean over heads + softmax.
// ---------------------------------------------------------------------------
__global__ __launch_bounds__(64) void fuse_kernel(
    const float* __restrict__ logits,  // [G][B][C]
    const float* __restrict__ Wf,      // [NH][C][C][G]
    const float* __restrict__ bf,      // [NH][C]
    float* __restrict__ out)
{
    const int b   = blockIdx.x;
    const int tid = threadIdx.x;

    __shared__ float s[C_ * G_];   // s[i*G + g]
    __shared__ float fl[C_];

    for (int t = tid; t < C_ * G_; t += 64) {
        int i = t >> 2, g = t & 3;
        s[t] = logits[((long)g * B_ + b) * C_ + i];
    }
    __syncthreads();

    if (tid < C_) {
        float acc = 0.f;
        for (int hd = 0; hd < NH_; ++hd) {
            float a = bf[hd * C_ + tid];
            const float* wrow = &Wf[((hd * C_ + tid) * C_) * G_];
#pragma unroll 5
            for (int i = 0; i < C_; ++i) {
#pragma unroll
                for (int g = 0; g < G_; ++g)
                    a += s[i * G_ + g] * wrow[i * G_ + g];
            }
            acc += a;
        }
        fl[tid] = acc * (1.0f / 3.0f);
    }
    __syncthreads();

    if (tid < C_) {
        float f = fl[tid];
        float m = -1e30f;
#pragma unroll
        for (int i = 0; i < C_; ++i) m = fmaxf(m, fl[i]);
        float ssum = 0.f;
#pragma unroll
        for (int i = 0; i < C_; ++i) ssum += expf(fl[i] - m);
        out[b * C_ + tid] = expf(f - m) / ssum;
        out[B_ * C_ + b * C_ + tid] = f;
    }
}

// ---------------------------------------------------------------------------
extern "C" void kernel_launch(void* const* d_in, const int* in_sizes, int n_in,
                              void* d_out, int out_size, void* d_ws, size_t ws_size,
                              hipStream_t stream)
{
    const int*   node_indices = (const int*)d_in[0];
    const int*   srcA         = (const int*)d_in[1];
    const int*   dstA         = (const int*)d_in[2];
    const int*   gidA         = (const int*)d_in[3];
    const float* ewA          = (const float*)d_in[4];
    const float* emb          = (const float*)d_in[5];
    const float* ep           = (const float*)d_in[6];
    const float* Wp           = (const float*)d_in[7];
    const float* bp           = (const float*)d_in[8];
    const float* Wc           = (const float*)d_in[9];
    const float* bc           = (const float*)d_in[10];
    const float* Wf           = (const float*)d_in[11];
    const float* bf           = (const float*)d_in[12];
    float*       out          = (float*)d_out;

    // Workspace layout:
    //   hA [N*H] f32 | hB [N*H] f32 | logits [G*B*C] f32 |
    //   deg/cnt [N] i32 | off [N+1] i32 | csr_src [E] i32 | csr_coef [E] f32
    float* hA       = (float*)d_ws;
    float* hB       = hA + (size_t)N_ * H_;
    float* logits   = hB + (size_t)N_ * H_;
    int*   deg_i    = (int*)(logits + (size_t)G_ * B_ * C_);
    int*   off      = deg_i + N_;
    int*   csr_src  = off + (N_ + 1);
    float* csr_coef = (float*)(csr_src + E_);
    // total ~107.5 MB

    for (int g = 0; g < G_; ++g) {
        const int*   idx = node_indices + (size_t)g * N_;
        const int*   src = srcA + (size_t)g * E_;
        const int*   dst = dstA + (size_t)g * E_;
        const int*   gid = gidA + (size_t)g * N_;
        const float* ew  = ewA + (size_t)g * E_;

        proj_kernel<<<(N_ + 63) / 64, 256, 0, stream>>>(
            idx, emb, Wp + (size_t)g * D_ * H_, bp + (size_t)g * H_, hA);

        // Build by-destination CSR
        hipMemsetAsync(deg_i, 0, N_ * sizeof(int), stream);
        deg_count_kernel<<<(E_ + 255) / 256, 256, 0, stream>>>(dst, deg_i, E_);
        scan_kernel<<<1, 1024, 0, stream>>>(deg_i, off);
        hipMemsetAsync(deg_i, 0, N_ * sizeof(int), stream);  // reuse as cnt
        scatter_kernel<<<(E_ + 255) / 256, 256, 0, stream>>>(
            src, dst, ew, ep + g, off, deg_i, csr_src, csr_coef, E_);

        // Two propagation steps (pure gather, no atomics)
        prop_gather_kernel<<<(N_ + 3) / 4, 256, 0, stream>>>(off, csr_src, csr_coef, hA, hB);
        prop_gather_kernel<<<(N_ + 3) / 4, 256, 0, stream>>>(off, csr_src, csr_coef, hB, hA);

        doc_cls_kernel<<<B_, 128, 0, stream>>>(
            gid, hA, Wc + (size_t)g * H_ * C_, bc + (size_t)g * C_,
            logits + (size_t)g * B_ * C_);
    }

    fuse_kernel<<<B_, 64, 0, stream>>>(logits, Wf, bf, out);
}

// Round 3
// 1996.853 us; speedup vs baseline: 1.6507x; 1.2178x over previous
//
#include <hip/hip_runtime.h>

// Problem constants (match reference)
#define G_  4
#define N_  100000
#define E_  500000
#define B_  512
#define V_  50000
#define D_  300
#define H_  128
#define C_  20
#define NH_ 3

__device__ __forceinline__ int lower_bound_i(const int* __restrict__ a, int n, int v) {
    int lo = 0, hi = n;
    while (lo < hi) {
        int mid = (lo + hi) >> 1;
        if (a[mid] < v) lo = mid + 1; else hi = mid;
    }
    return lo;
}

// ---------------------------------------------------------------------------
// Table projection GEMM: P[g][v][h] = sum_k emb[v][k] * Wp[g][k][h] + bp[g][h]
// M=V=50000, K=300 (tiled as 19x16 with zero-padding), N=128 per graph.
// BM=128, BN=128, BK=16; 256 threads, 8x8 per thread (split 4+64 tiling).
// LDS: As transposed [16][132], Bs [16][132] -> ~17KB, all accesses <=2-way.
// ---------------------------------------------------------------------------
__global__ __launch_bounds__(256) void table_gemm_kernel(
    const float* __restrict__ A,    // emb_table [V][300]
    const float* __restrict__ Wp,   // [ng][300][128]
    const float* __restrict__ bp,   // [ng][128]
    float* __restrict__ P)          // [ng][V][128]
{
    __shared__ __align__(16) float As[16][128 + 4];  // As[k][m]
    __shared__ __align__(16) float Bs[16][128 + 4];  // Bs[k][n]

    const int t    = threadIdx.x;
    const int row0 = blockIdx.x * 128;
    const int g    = blockIdx.y;

    const float* Bg = Wp + (size_t)g * D_ * H_;
    float*       Pg = P  + (size_t)g * V_ * H_;

    const int ty = t >> 4;   // 0..15
    const int tx = t & 15;   // 0..15

    float acc[8][8];
#pragma unroll
    for (int i = 0; i < 8; ++i)
#pragma unroll
        for (int j = 0; j < 8; ++j) acc[i][j] = 0.f;

    for (int k0 = 0; k0 < 304; k0 += 16) {
        // --- load A tile (transposed into LDS) ---
#pragma unroll
        for (int i = 0; i < 2; ++i) {
            int flat = t + i * 256;
            int m  = flat >> 2;        // 0..127
            int kq = flat & 3;         // 0..3
            int row = row0 + m;
            int k   = k0 + kq * 4;
            float4 v = make_float4(0.f, 0.f, 0.f, 0.f);
            if (row < V_ && k <= D_ - 4)
                v = *reinterpret_cast<const float4*>(&A[(size_t)row * D_ + k]);
            As[kq * 4 + 0][m] = v.x;
            As[kq * 4 + 1][m] = v.y;
            As[kq * 4 + 2][m] = v.z;
            As[kq * 4 + 3][m] = v.w;
        }
        // --- load B tile ---
#pragma unroll
        for (int i = 0; i < 2; ++i) {
            int flat = t + i * 256;
            int k  = flat >> 5;        // 0..15
            int nq = flat & 31;        // 0..31
            float4 v = make_float4(0.f, 0.f, 0.f, 0.f);
            if (k0 + k < D_)
                v = *reinterpret_cast<const float4*>(&Bg[(size_t)(k0 + k) * H_ + nq * 4]);
            *reinterpret_cast<float4*>(&Bs[k][nq * 4]) = v;
        }
        __syncthreads();

#pragma unroll
        for (int k = 0; k < 16; ++k) {
            float4 a0 = *reinterpret_cast<const float4*>(&As[k][ty * 4]);
            float4 a1 = *reinterpret_cast<const float4*>(&As[k][ty * 4 + 64]);
            float4 b0 = *reinterpret_cast<const float4*>(&Bs[k][tx * 4]);
            float4 b1 = *reinterpret_cast<const float4*>(&Bs[k][tx * 4 + 64]);
            float av[8] = {a0.x, a0.y, a0.z, a0.w, a1.x, a1.y, a1.z, a1.w};
            float bv[8] = {b0.x, b0.y, b0.z, b0.w, b1.x, b1.y, b1.z, b1.w};
#pragma unroll
            for (int i = 0; i < 8; ++i)
#pragma unroll
                for (int j = 0; j < 8; ++j)
                    acc[i][j] += av[i] * bv[j];
        }
        __syncthreads();
    }

    // epilogue: add bias, store
#pragma unroll
    for (int i = 0; i < 8; ++i) {
        int row = row0 + ((i < 4) ? (ty * 4 + i) : (64 + ty * 4 + i - 4));
        if (row >= V_) continue;
        int c0 = tx * 4, c1 = tx * 4 + 64;
        float4 v0, v1;
        v0.x = acc[i][0] + bp[g * H_ + c0 + 0];
        v0.y = acc[i][1] + bp[g * H_ + c0 + 1];
        v0.z = acc[i][2] + bp[g * H_ + c0 + 2];
        v0.w = acc[i][3] + bp[g * H_ + c0 + 3];
        v1.x = acc[i][4] + bp[g * H_ + c1 + 0];
        v1.y = acc[i][5] + bp[g * H_ + c1 + 1];
        v1.z = acc[i][6] + bp[g * H_ + c1 + 2];
        v1.w = acc[i][7] + bp[g * H_ + c1 + 3];
        *reinterpret_cast<float4*>(&Pg[(size_t)row * H_ + c0]) = v0;
        *reinterpret_cast<float4*>(&Pg[(size_t)row * H_ + c1]) = v1;
    }
}

// ---------------------------------------------------------------------------
// CSR build: in-degree count -> exclusive scan -> scatter by dst.
// scatter also precomputes csr_vsrc[e] = idx[src[e]] (embedding row of source)
// ---------------------------------------------------------------------------
__global__ __launch_bounds__(256) void deg_count_kernel(const int* __restrict__ dst,
                                                        int* __restrict__ deg, int E)
{
    int e = blockIdx.x * 256 + threadIdx.x;
    if (e < E) atomicAdd(&deg[dst[e]], 1);
}

__global__ __launch_bounds__(1024) void scan_kernel(const int* __restrict__ deg,
                                                    int* __restrict__ off)
{
    __shared__ int part[1024];
    const int CH = (N_ + 1023) / 1024;
    const int t = threadIdx.x;
    const int begin = t * CH;
    const int end   = min(begin + CH, N_);

    int s = 0;
    for (int i = begin; i < end; ++i) s += deg[i];
    part[t] = s;
    __syncthreads();

    for (int ofs = 1; ofs < 1024; ofs <<= 1) {
        int v = 0;
        if (t >= ofs) v = part[t - ofs];
        __syncthreads();
        if (t >= ofs) part[t] += v;
        __syncthreads();
    }

    int run = (t > 0) ? part[t - 1] : 0;
    for (int i = begin; i < end; ++i) { off[i] = run; run += deg[i]; }
    if (t == 1023) off[N_] = part[1023];
}

__global__ __launch_bounds__(256) void scatter_kernel(
    const int* __restrict__ src, const int* __restrict__ dst,
    const float* __restrict__ ew, const float* __restrict__ ep,
    const int* __restrict__ idx_g, const int* __restrict__ off,
    int* __restrict__ cnt, int* __restrict__ csr_src,
    int* __restrict__ csr_vsrc, float* __restrict__ csr_coef, int E)
{
    int e = blockIdx.x * 256 + threadIdx.x;
    if (e >= E) return;
    int s = src[e];
    int d = dst[e];
    int pos = off[d] + atomicAdd(&cnt[d], 1);
    csr_src[pos]  = s;
    csr_vsrc[pos] = idx_g[s];
    float w = ep[0] * ew[e];
    csr_coef[pos] = fmaxf(w, 0.f);
}

// ---------------------------------------------------------------------------
// Propagation step 1 (reads the projected TABLE P via embedding indices):
//   hB[n] = P[idx[n]] + inv_deg[n] * sum_e coef[e] * P[csr_vsrc[e]]
// ---------------------------------------------------------------------------
__global__ __launch_bounds__(256) void prop1_kernel(
    const int* __restrict__ idx_g, const int* __restrict__ off,
    const int* __restrict__ csr_vsrc, const float* __restrict__ csr_coef,
    const float* __restrict__ P, float* __restrict__ hB)
{
    const int n = blockIdx.x * 4 + (threadIdx.x >> 6);
    if (n >= N_) return;
    const int lane = threadIdx.x & 63;

    const int lo = off[n], hi = off[n + 1];
    float2 acc = make_float2(0.f, 0.f);
    for (int i = lo; i < hi; ++i) {
        const int v   = csr_vsrc[i];
        const float c = csr_coef[i];
        const float2 hv = *reinterpret_cast<const float2*>(&P[(size_t)v * H_ + lane * 2]);
        acc.x += c * hv.x;
        acc.y += c * hv.y;
    }
    const float inv = (hi > lo) ? 1.0f / (float)(hi - lo) : 0.f;
    const float2 self = *reinterpret_cast<const float2*>(&P[(size_t)idx_g[n] * H_ + lane * 2]);
    float2 o = make_float2(self.x + inv * acc.x, self.y + inv * acc.y);
    *reinterpret_cast<float2*>(&hB[(size_t)n * H_ + lane * 2]) = o;
}

// ---------------------------------------------------------------------------
// Propagation step 2 (node-indexed gather):
//   hA[n] = hB[n] + inv_deg[n] * sum_e coef[e] * hB[csr_src[e]]
// ---------------------------------------------------------------------------
__global__ __launch_bounds__(256) void prop2_kernel(
    const int* __restrict__ off, const int* __restrict__ csr_src,
    const float* __restrict__ csr_coef,
    const float* __restrict__ h_old, float* __restrict__ h_new)
{
    const int n = blockIdx.x * 4 + (threadIdx.x >> 6);
    if (n >= N_) return;
    const int lane = threadIdx.x & 63;

    const int lo = off[n], hi = off[n + 1];
    float2 acc = make_float2(0.f, 0.f);
    for (int i = lo; i < hi; ++i) {
        const int s   = csr_src[i];
        const float c = csr_coef[i];
        const float2 v = *reinterpret_cast<const float2*>(&h_old[(size_t)s * H_ + lane * 2]);
        acc.x += c * v.x;
        acc.y += c * v.y;
    }
    const float inv = (hi > lo) ? 1.0f / (float)(hi - lo) : 0.f;
    const float2 hv = *reinterpret_cast<const float2*>(&h_old[(size_t)n * H_ + lane * 2]);
    float2 o = make_float2(hv.x + inv * acc.x, hv.y + inv * acc.y);
    *reinterpret_cast<float2*>(&h_new[(size_t)n * H_ + lane * 2]) = o;
}

// ---------------------------------------------------------------------------
// Doc pooling + ReLU + classifier
// ---------------------------------------------------------------------------
__global__ __launch_bounds__(128) void doc_cls_kernel(
    const int* __restrict__ gid, const float* __restrict__ h,
    const float* __restrict__ Wc, const float* __restrict__ bc,
    float* __restrict__ logits)
{
    const int b   = blockIdx.x;
    const int tid = threadIdx.x;

    int lo = lower_bound_i(gid, N_, b);
    int hi = lower_bound_i(gid, N_, b + 1);

    float s = 0.f;
    for (int n = lo; n < hi; ++n) s += h[(long)n * H_ + tid];

    float cnt = (float)(hi - lo);
    float doc = s / fmaxf(cnt, 1.0f);

    __shared__ float sdoc[H_];
    sdoc[tid] = fmaxf(doc, 0.f);
    __syncthreads();

    if (tid < C_) {
        float acc = bc[tid];
#pragma unroll 8
        for (int hh = 0; hh < H_; ++hh) acc += sdoc[hh] * Wc[hh * C_ + tid];
        logits[b * C_ + tid] = acc;
    }
}

// ---------------------------------------------------------------------------
// Head fusion + mean over heads + softmax
// ---------------------------------------------------------------------------
__global__ __launch_bounds__(64) void fuse_kernel(
    const float* __restrict__ logits,  // [G][B][C]
    const float* __restrict__ Wf,      // [NH][C][C][G]
    const float* __restrict__ bf,      // [NH][C]
    float* __restrict__ out)
{
    const int b   = blockIdx.x;
    const int tid = threadIdx.x;

    __shared__ float s[C_ * G_];
    __shared__ float fl[C_];

    for (int t = tid; t < C_ * G_; t += 64) {
        int i = t >> 2, g = t & 3;
        s[t] = logits[((long)g * B_ + b) * C_ + i];
    }
    __syncthreads();

    if (tid < C_) {
        float acc = 0.f;
        for (int hd = 0; hd < NH_; ++hd) {
            float a = bf[hd * C_ + tid];
            const float* wrow = &Wf[((hd * C_ + tid) * C_) * G_];
#pragma unroll 5
            for (int i = 0; i < C_; ++i) {
#pragma unroll
                for (int g = 0; g < G_; ++g)
                    a += s[i * G_ + g] * wrow[i * G_ + g];
            }
            acc += a;
        }
        fl[tid] = acc * (1.0f / 3.0f);
    }
    __syncthreads();

    if (tid < C_) {
        float f = fl[tid];
        float m = -1e30f;
#pragma unroll
        for (int i = 0; i < C_; ++i) m = fmaxf(m, fl[i]);
        float ssum = 0.f;
#pragma unroll
        for (int i = 0; i < C_; ++i) ssum += expf(fl[i] - m);
        out[b * C_ + tid] = expf(f - m) / ssum;
        out[B_ * C_ + b * C_ + tid] = f;
    }
}

// ---------------------------------------------------------------------------
extern "C" void kernel_launch(void* const* d_in, const int* in_sizes, int n_in,
                              void* d_out, int out_size, void* d_ws, size_t ws_size,
                              hipStream_t stream)
{
    const int*   node_indices = (const int*)d_in[0];
    const int*   srcA         = (const int*)d_in[1];
    const int*   dstA         = (const int*)d_in[2];
    const int*   gidA         = (const int*)d_in[3];
    const float* ewA          = (const float*)d_in[4];
    const float* emb          = (const float*)d_in[5];
    const float* ep           = (const float*)d_in[6];
    const float* Wp           = (const float*)d_in[7];
    const float* bp           = (const float*)d_in[8];
    const float* Wc           = (const float*)d_in[9];
    const float* bc           = (const float*)d_in[10];
    const float* Wf           = (const float*)d_in[11];
    const float* bf           = (const float*)d_in[12];
    float*       out          = (float*)d_out;

    // Workspace layout (256B-aligned blocks)
    char* wp0 = (char*)d_ws;
    auto alloc = [&](size_t bytes) {
        void* r = (void*)wp0;
        wp0 += (bytes + 255) & ~(size_t)255;
        return r;
    };
    float* hA       = (float*)alloc((size_t)N_ * H_ * 4);
    float* hB       = (float*)alloc((size_t)N_ * H_ * 4);
    float* logits   = (float*)alloc((size_t)G_ * B_ * C_ * 4);
    int*   deg_i    = (int*)  alloc((size_t)N_ * 4);
    int*   off      = (int*)  alloc((size_t)(N_ + 1) * 4);
    int*   csr_src  = (int*)  alloc((size_t)E_ * 4);
    int*   csr_vsrc = (int*)  alloc((size_t)E_ * 4);
    float* csr_coef = (float*)alloc((size_t)E_ * 4);

    const size_t pbytes = (size_t)V_ * H_ * 4;   // 25.6 MB per graph
    size_t used = (size_t)(wp0 - (char*)d_ws);
    size_t avail = (ws_size > used) ? ws_size - used : 0;

    int ng;
    float* P;
    if (avail >= 4 * pbytes + 1024) {
        ng = 4; P = (float*)alloc(4 * pbytes);
    } else if (avail >= 2 * pbytes + 1024) {
        ng = 2; P = (float*)alloc(2 * pbytes);
    } else {
        // Alias P onto hA: P (25.6MB) < hA (51.2MB). Safe: per graph, P is
        // consumed by prop1 before prop2 writes hA; GEMM re-fills P next graph.
        ng = 1; P = hA;
    }

    for (int gbase = 0; gbase < G_; gbase += ng) {
        table_gemm_kernel<<<dim3((V_ + 127) / 128, ng), 256, 0, stream>>>(
            emb, Wp + (size_t)gbase * D_ * H_, bp + (size_t)gbase * H_, P);

        for (int gi = 0; gi < ng; ++gi) {
            const int g = gbase + gi;
            const int*   idx = node_indices + (size_t)g * N_;
            const int*   src = srcA + (size_t)g * E_;
            const int*   dst = dstA + (size_t)g * E_;
            const int*   gid = gidA + (size_t)g * N_;
            const float* ew  = ewA + (size_t)g * E_;
            const float* Pg  = P + (size_t)gi * V_ * H_;

            hipMemsetAsync(deg_i, 0, N_ * sizeof(int), stream);
            deg_count_kernel<<<(E_ + 255) / 256, 256, 0, stream>>>(dst, deg_i, E_);
            scan_kernel<<<1, 1024, 0, stream>>>(deg_i, off);
            hipMemsetAsync(deg_i, 0, N_ * sizeof(int), stream);  // reuse as cnt
            scatter_kernel<<<(E_ + 255) / 256, 256, 0, stream>>>(
                src, dst, ew, ep + g, idx, off, deg_i, csr_src, csr_vsrc, csr_coef, E_);

            prop1_kernel<<<(N_ + 3) / 4, 256, 0, stream>>>(
                idx, off, csr_vsrc, csr_coef, Pg, hB);
            prop2_kernel<<<(N_ + 3) / 4, 256, 0, stream>>>(
                off, csr_src, csr_coef, hB, hA);

            doc_cls_kernel<<<B_, 128, 0, stream>>>(
                gid, hA, Wc + (size_t)g * H_ * C_, bc + (size_t)g * C_,
                logits + (size_t)g * B_ * C_);
        }
    }

    fuse_kernel<<<B_, 64, 0, stream>>>(logits, Wf, bf, out);
}

// Round 4
// 1163.896 us; speedup vs baseline: 2.8320x; 1.7157x over previous
//
#include <hip/hip_runtime.h>

// Problem constants (match reference)
#define G_  4
#define N_  100000
#define E_  500000
#define B_  512
#define V_  50000
#define D_  300
#define H_  128
#define C_  20
#define NH_ 3

#define SCB_  512                       // elems per scan block
#define NBLK_ ((N_ + SCB_ - 1) / SCB_)  // 196

__device__ __forceinline__ int lower_bound_i(const int* __restrict__ a, int n, int v) {
    int lo = 0, hi = n;
    while (lo < hi) {
        int mid = (lo + hi) >> 1;
        if (a[mid] < v) lo = mid + 1; else hi = mid;
    }
    return lo;
}

// ---------------------------------------------------------------------------
// Table projection GEMM: P[g][v][h] = sum_k emb[v][k] * Wp[g][k][h] + bp[g][h]
// grid = (ng, V/128): blockIdx.x = graph so blocks sharing an A-tile dispatch
// adjacently (L2/L3 A reuse). BM=128, BN=128, BK=16, 8x8/thread.
// ---------------------------------------------------------------------------
__global__ __launch_bounds__(256) void table_gemm_kernel(
    const float* __restrict__ A,    // emb_table [V][300]
    const float* __restrict__ Wp,   // [ng][300][128]
    const float* __restrict__ bp,   // [ng][128]
    float* __restrict__ P)          // [ng][V][128]
{
    __shared__ __align__(16) float As[16][128 + 4];  // As[k][m]
    __shared__ __align__(16) float Bs[16][128 + 4];  // Bs[k][n]

    const int t    = threadIdx.x;
    const int g    = blockIdx.x;
    const int row0 = blockIdx.y * 128;

    const float* Bg = Wp + (size_t)g * D_ * H_;
    float*       Pg = P  + (size_t)g * V_ * H_;

    const int ty = t >> 4;   // 0..15
    const int tx = t & 15;   // 0..15

    float acc[8][8];
#pragma unroll
    for (int i = 0; i < 8; ++i)
#pragma unroll
        for (int j = 0; j < 8; ++j) acc[i][j] = 0.f;

    for (int k0 = 0; k0 < 304; k0 += 16) {
        // --- load A tile (transposed into LDS) ---
#pragma unroll
        for (int i = 0; i < 2; ++i) {
            int flat = t + i * 256;
            int m  = flat >> 2;        // 0..127
            int kq = flat & 3;         // 0..3
            int row = row0 + m;
            int k   = k0 + kq * 4;
            float4 v = make_float4(0.f, 0.f, 0.f, 0.f);
            if (row < V_ && k <= D_ - 4)
                v = *reinterpret_cast<const float4*>(&A[(size_t)row * D_ + k]);
            As[kq * 4 + 0][m] = v.x;
            As[kq * 4 + 1][m] = v.y;
            As[kq * 4 + 2][m] = v.z;
            As[kq * 4 + 3][m] = v.w;
        }
        // --- load B tile ---
#pragma unroll
        for (int i = 0; i < 2; ++i) {
            int flat = t + i * 256;
            int k  = flat >> 5;        // 0..15
            int nq = flat & 31;        // 0..31
            float4 v = make_float4(0.f, 0.f, 0.f, 0.f);
            if (k0 + k < D_)
                v = *reinterpret_cast<const float4*>(&Bg[(size_t)(k0 + k) * H_ + nq * 4]);
            *reinterpret_cast<float4*>(&Bs[k][nq * 4]) = v;
        }
        __syncthreads();

#pragma unroll
        for (int k = 0; k < 16; ++k) {
            float4 a0 = *reinterpret_cast<const float4*>(&As[k][ty * 4]);
            float4 a1 = *reinterpret_cast<const float4*>(&As[k][ty * 4 + 64]);
            float4 b0 = *reinterpret_cast<const float4*>(&Bs[k][tx * 4]);
            float4 b1 = *reinterpret_cast<const float4*>(&Bs[k][tx * 4 + 64]);
            float av[8] = {a0.x, a0.y, a0.z, a0.w, a1.x, a1.y, a1.z, a1.w};
            float bv[8] = {b0.x, b0.y, b0.z, b0.w, b1.x, b1.y, b1.z, b1.w};
#pragma unroll
            for (int i = 0; i < 8; ++i)
#pragma unroll
                for (int j = 0; j < 8; ++j)
                    acc[i][j] += av[i] * bv[j];
        }
        __syncthreads();
    }

#pragma unroll
    for (int i = 0; i < 8; ++i) {
        int row = row0 + ((i < 4) ? (ty * 4 + i) : (64 + ty * 4 + i - 4));
        if (row >= V_) continue;
        int c0 = tx * 4, c1 = tx * 4 + 64;
        float4 v0, v1;
        v0.x = acc[i][0] + bp[g * H_ + c0 + 0];
        v0.y = acc[i][1] + bp[g * H_ + c0 + 1];
        v0.z = acc[i][2] + bp[g * H_ + c0 + 2];
        v0.w = acc[i][3] + bp[g * H_ + c0 + 3];
        v1.x = acc[i][4] + bp[g * H_ + c1 + 0];
        v1.y = acc[i][5] + bp[g * H_ + c1 + 1];
        v1.z = acc[i][6] + bp[g * H_ + c1 + 2];
        v1.w = acc[i][7] + bp[g * H_ + c1 + 3];
        *reinterpret_cast<float4*>(&Pg[(size_t)row * H_ + c0]) = v0;
        *reinterpret_cast<float4*>(&Pg[(size_t)row * H_ + c1]) = v1;
    }
}

// ---------------------------------------------------------------------------
// Batched CSR build over all G graphs (grid.y = g):
//   deg_count -> scan1 (block sums) -> scan2 (scan sums) -> scan3 (local scan,
//   writes off, zeroes deg for reuse as cnt) -> scatter
// ---------------------------------------------------------------------------
__global__ __launch_bounds__(256) void deg_count_kernel(const int* __restrict__ dstA,
                                                        int* __restrict__ deg)
{
    const int g = blockIdx.y;
    int e = blockIdx.x * 256 + threadIdx.x;
    if (e < E_) atomicAdd(&deg[g * N_ + dstA[(size_t)g * E_ + e]], 1);
}

__global__ __launch_bounds__(512) void scan1_kernel(const int* __restrict__ deg,
                                                    int* __restrict__ bsum)
{
    __shared__ int sh[512];
    const int g = blockIdx.y, b = blockIdx.x, t = threadIdx.x;
    int i = b * SCB_ + t;
    sh[t] = (i < N_) ? deg[g * N_ + i] : 0;
    __syncthreads();
#pragma unroll
    for (int ofs = 256; ofs > 0; ofs >>= 1) {
        if (t < ofs) sh[t] += sh[t + ofs];
        __syncthreads();
    }
    if (t == 0) bsum[g * NBLK_ + b] = sh[0];
}

__global__ __launch_bounds__(256) void scan2_kernel(const int* __restrict__ bsum,
                                                    int* __restrict__ bpre,
                                                    int* __restrict__ off)
{
    __shared__ int sh[256];
    const int g = blockIdx.x, t = threadIdx.x;
    int v = (t < NBLK_) ? bsum[g * NBLK_ + t] : 0;
    sh[t] = v;
    __syncthreads();
#pragma unroll
    for (int ofs = 1; ofs < 256; ofs <<= 1) {
        int u = (t >= ofs) ? sh[t - ofs] : 0;
        __syncthreads();
        sh[t] += u;
        __syncthreads();
    }
    if (t < NBLK_) bpre[g * (NBLK_ + 1) + t + 1] = sh[t];
    if (t == 0) {
        bpre[g * (NBLK_ + 1)] = 0;
        off[(size_t)g * (N_ + 1) + N_] = sh[NBLK_ - 1];
    }
}

__global__ __launch_bounds__(512) void scan3_kernel(int* __restrict__ deg,
                                                    const int* __restrict__ bpre,
                                                    int* __restrict__ off)
{
    __shared__ int sh[512];
    const int g = blockIdx.y, b = blockIdx.x, t = threadIdx.x;
    int i = b * SCB_ + t;
    int v = (i < N_) ? deg[g * N_ + i] : 0;
    sh[t] = v;
    __syncthreads();
#pragma unroll
    for (int ofs = 1; ofs < 512; ofs <<= 1) {
        int u = (t >= ofs) ? sh[t - ofs] : 0;
        __syncthreads();
        sh[t] += u;
        __syncthreads();
    }
    if (i < N_) {
        off[(size_t)g * (N_ + 1) + i] = bpre[g * (NBLK_ + 1) + b] + sh[t] - v;
        deg[g * N_ + i] = 0;   // becomes cnt for scatter
    }
}

__global__ __launch_bounds__(256) void scatter_kernel(
    const int* __restrict__ srcA, const int* __restrict__ dstA,
    const float* __restrict__ ewA, const float* __restrict__ ep,
    const int* __restrict__ idxA, const int* __restrict__ off,
    int* __restrict__ cnt, int* __restrict__ csr_src,
    int* __restrict__ csr_vsrc, float* __restrict__ csr_coef)
{
    const int g = blockIdx.y;
    int e = blockIdx.x * 256 + threadIdx.x;
    if (e >= E_) return;
    int s = srcA[(size_t)g * E_ + e];
    int d = dstA[(size_t)g * E_ + e];
    int pos = off[(size_t)g * (N_ + 1) + d] + atomicAdd(&cnt[g * N_ + d], 1);
    csr_src[(size_t)g * E_ + pos]  = s;
    csr_vsrc[(size_t)g * E_ + pos] = idxA[(size_t)g * N_ + s];
    float w = ep[g] * ewA[(size_t)g * E_ + e];
    csr_coef[(size_t)g * E_ + pos] = fmaxf(w, 0.f);
}

// ---------------------------------------------------------------------------
// Propagation step 1: hB[n] = P[idx[n]] + inv_deg * sum coef * P[vsrc]
// 32 lanes per node (float4/lane), 8 nodes/block, 4-deep gather pipeline.
// ---------------------------------------------------------------------------
__global__ __launch_bounds__(256) void prop1_kernel(
    const int* __restrict__ idx_g, const int* __restrict__ off,
    const int* __restrict__ csr_vsrc, const float* __restrict__ csr_coef,
    const float* __restrict__ P, float* __restrict__ hB)
{
    const int n = blockIdx.x * 8 + (threadIdx.x >> 5);
    if (n >= N_) return;
    const int lane = threadIdx.x & 31;
    const int col  = lane * 4;

    const int lo = off[n], hi = off[n + 1];
    const float4 self = *reinterpret_cast<const float4*>(
        &P[(size_t)idx_g[n] * H_ + col]);

    float4 acc = make_float4(0.f, 0.f, 0.f, 0.f);
    int i = lo;
    for (; i + 4 <= hi; i += 4) {
        int   s0 = csr_vsrc[i],     s1 = csr_vsrc[i + 1];
        int   s2 = csr_vsrc[i + 2], s3 = csr_vsrc[i + 3];
        float c0 = csr_coef[i],     c1 = csr_coef[i + 1];
        float c2 = csr_coef[i + 2], c3 = csr_coef[i + 3];
        float4 v0 = *reinterpret_cast<const float4*>(&P[(size_t)s0 * H_ + col]);
        float4 v1 = *reinterpret_cast<const float4*>(&P[(size_t)s1 * H_ + col]);
        float4 v2 = *reinterpret_cast<const float4*>(&P[(size_t)s2 * H_ + col]);
        float4 v3 = *reinterpret_cast<const float4*>(&P[(size_t)s3 * H_ + col]);
        acc.x += c0 * v0.x + c1 * v1.x + c2 * v2.x + c3 * v3.x;
        acc.y += c0 * v0.y + c1 * v1.y + c2 * v2.y + c3 * v3.y;
        acc.z += c0 * v0.z + c1 * v1.z + c2 * v2.z + c3 * v3.z;
        acc.w += c0 * v0.w + c1 * v1.w + c2 * v2.w + c3 * v3.w;
    }
    for (; i < hi; ++i) {
        int   s = csr_vsrc[i];
        float c = csr_coef[i];
        float4 v = *reinterpret_cast<const float4*>(&P[(size_t)s * H_ + col]);
        acc.x += c * v.x; acc.y += c * v.y; acc.z += c * v.z; acc.w += c * v.w;
    }
    const float inv = (hi > lo) ? 1.0f / (float)(hi - lo) : 0.f;
    float4 o = make_float4(self.x + inv * acc.x, self.y + inv * acc.y,
                           self.z + inv * acc.z, self.w + inv * acc.w);
    *reinterpret_cast<float4*>(&hB[(size_t)n * H_ + col]) = o;
}

// ---------------------------------------------------------------------------
// Propagation step 2: hA[n] = hB[n] + inv_deg * sum coef * hB[src]
// ---------------------------------------------------------------------------
__global__ __launch_bounds__(256) void prop2_kernel(
    const int* __restrict__ off, const int* __restrict__ csr_src,
    const float* __restrict__ csr_coef,
    const float* __restrict__ h_old, float* __restrict__ h_new)
{
    const int n = blockIdx.x * 8 + (threadIdx.x >> 5);
    if (n >= N_) return;
    const int lane = threadIdx.x & 31;
    const int col  = lane * 4;

    const int lo = off[n], hi = off[n + 1];
    const float4 self = *reinterpret_cast<const float4*>(
        &h_old[(size_t)n * H_ + col]);

    float4 acc = make_float4(0.f, 0.f, 0.f, 0.f);
    int i = lo;
    for (; i + 4 <= hi; i += 4) {
        int   s0 = csr_src[i],     s1 = csr_src[i + 1];
        int   s2 = csr_src[i + 2], s3 = csr_src[i + 3];
        float c0 = csr_coef[i],    c1 = csr_coef[i + 1];
        float c2 = csr_coef[i + 2], c3 = csr_coef[i + 3];
        float4 v0 = *reinterpret_cast<const float4*>(&h_old[(size_t)s0 * H_ + col]);
        float4 v1 = *reinterpret_cast<const float4*>(&h_old[(size_t)s1 * H_ + col]);
        float4 v2 = *reinterpret_cast<const float4*>(&h_old[(size_t)s2 * H_ + col]);
        float4 v3 = *reinterpret_cast<const float4*>(&h_old[(size_t)s3 * H_ + col]);
        acc.x += c0 * v0.x + c1 * v1.x + c2 * v2.x + c3 * v3.x;
        acc.y += c0 * v0.y + c1 * v1.y + c2 * v2.y + c3 * v3.y;
        acc.z += c0 * v0.z + c1 * v1.z + c2 * v2.z + c3 * v3.z;
        acc.w += c0 * v0.w + c1 * v1.w + c2 * v2.w + c3 * v3.w;
    }
    for (; i < hi; ++i) {
        int   s = csr_src[i];
        float c = csr_coef[i];
        float4 v = *reinterpret_cast<const float4*>(&h_old[(size_t)s * H_ + col]);
        acc.x += c * v.x; acc.y += c * v.y; acc.z += c * v.z; acc.w += c * v.w;
    }
    const float inv = (hi > lo) ? 1.0f / (float)(hi - lo) : 0.f;
    float4 o = make_float4(self.x + inv * acc.x, self.y + inv * acc.y,
                           self.z + inv * acc.z, self.w + inv * acc.w);
    *reinterpret_cast<float4*>(&h_new[(size_t)n * H_ + col]) = o;
}

// ---------------------------------------------------------------------------
// Doc pooling + ReLU + classifier
// ---------------------------------------------------------------------------
__global__ __launch_bounds__(128) void doc_cls_kernel(
    const int* __restrict__ gid, const float* __restrict__ h,
    const float* __restrict__ Wc, const float* __restrict__ bc,
    float* __restrict__ logits)
{
    const int b   = blockIdx.x;
    const int tid = threadIdx.x;

    int lo = lower_bound_i(gid, N_, b);
    int hi = lower_bound_i(gid, N_, b + 1);

    float s = 0.f;
    for (int n = lo; n < hi; ++n) s += h[(long)n * H_ + tid];

    float cnt = (float)(hi - lo);
    float doc = s / fmaxf(cnt, 1.0f);

    __shared__ float sdoc[H_];
    sdoc[tid] = fmaxf(doc, 0.f);
    __syncthreads();

    if (tid < C_) {
        float acc = bc[tid];
#pragma unroll 8
        for (int hh = 0; hh < H_; ++hh) acc += sdoc[hh] * Wc[hh * C_ + tid];
        logits[b * C_ + tid] = acc;
    }
}

// ---------------------------------------------------------------------------
// Head fusion + mean over heads + softmax
// ---------------------------------------------------------------------------
__global__ __launch_bounds__(64) void fuse_kernel(
    const float* __restrict__ logits,  // [G][B][C]
    const float* __restrict__ Wf,      // [NH][C][C][G]
    const float* __restrict__ bf,      // [NH][C]
    float* __restrict__ out)
{
    const int b   = blockIdx.x;
    const int tid = threadIdx.x;

    __shared__ float s[C_ * G_];
    __shared__ float fl[C_];

    for (int t = tid; t < C_ * G_; t += 64) {
        int i = t >> 2, g = t & 3;
        s[t] = logits[((long)g * B_ + b) * C_ + i];
    }
    __syncthreads();

    if (tid < C_) {
        float acc = 0.f;
        for (int hd = 0; hd < NH_; ++hd) {
            float a = bf[hd * C_ + tid];
            const float* wrow = &Wf[((hd * C_ + tid) * C_) * G_];
#pragma unroll 5
            for (int i = 0; i < C_; ++i) {
#pragma unroll
                for (int g = 0; g < G_; ++g)
                    a += s[i * G_ + g] * wrow[i * G_ + g];
            }
            acc += a;
        }
        fl[tid] = acc * (1.0f / 3.0f);
    }
    __syncthreads();

    if (tid < C_) {
        float f = fl[tid];
        float m = -1e30f;
#pragma unroll
        for (int i = 0; i < C_; ++i) m = fmaxf(m, fl[i]);
        float ssum = 0.f;
#pragma unroll
        for (int i = 0; i < C_; ++i) ssum += expf(fl[i] - m);
        out[b * C_ + tid] = expf(f - m) / ssum;
        out[B_ * C_ + b * C_ + tid] = f;
    }
}

// ---------------------------------------------------------------------------
extern "C" void kernel_launch(void* const* d_in, const int* in_sizes, int n_in,
                              void* d_out, int out_size, void* d_ws, size_t ws_size,
                              hipStream_t stream)
{
    const int*   node_indices = (const int*)d_in[0];
    const int*   srcA         = (const int*)d_in[1];
    const int*   dstA         = (const int*)d_in[2];
    const int*   gidA         = (const int*)d_in[3];
    const float* ewA          = (const float*)d_in[4];
    const float* emb          = (const float*)d_in[5];
    const float* ep           = (const float*)d_in[6];
    const float* Wp           = (const float*)d_in[7];
    const float* bp           = (const float*)d_in[8];
    const float* Wc           = (const float*)d_in[9];
    const float* bc           = (const float*)d_in[10];
    const float* Wf           = (const float*)d_in[11];
    const float* bf           = (const float*)d_in[12];
    float*       out          = (float*)d_out;

    // Workspace layout (256B-aligned blocks)
    char* wp0 = (char*)d_ws;
    auto alloc = [&](size_t bytes) {
        void* r = (void*)wp0;
        wp0 += (bytes + 255) & ~(size_t)255;
        return r;
    };
    float* hA       = (float*)alloc((size_t)N_ * H_ * 4);
    float* hB       = (float*)alloc((size_t)N_ * H_ * 4);
    float* logits   = (float*)alloc((size_t)G_ * B_ * C_ * 4);
    int*   deg_i    = (int*)  alloc((size_t)G_ * N_ * 4);           // also cnt
    int*   off      = (int*)  alloc((size_t)G_ * (N_ + 1) * 4);
    int*   bsum     = (int*)  alloc((size_t)G_ * NBLK_ * 4);
    int*   bpre     = (int*)  alloc((size_t)G_ * (NBLK_ + 1) * 4);
    int*   csr_src  = (int*)  alloc((size_t)G_ * E_ * 4);
    int*   csr_vsrc = (int*)  alloc((size_t)G_ * E_ * 4);
    float* csr_coef = (float*)alloc((size_t)G_ * E_ * 4);

    const size_t pbytes = (size_t)V_ * H_ * 4;   // 25.6 MB per graph
    size_t used  = (size_t)(wp0 - (char*)d_ws);
    size_t avail = (ws_size > used) ? ws_size - used : 0;

    int ng;
    float* P;
    if (avail >= 4 * pbytes + 1024) {
        ng = 4; P = (float*)alloc(4 * pbytes);
    } else if (avail >= 2 * pbytes + 1024) {
        ng = 2; P = (float*)alloc(2 * pbytes);
    } else {
        // Alias P onto hA (safe: P consumed by prop1 before prop2 writes hA)
        ng = 1; P = hA;
    }

    // ---- batched CSR build for all graphs ----
    hipMemsetAsync(deg_i, 0, (size_t)G_ * N_ * sizeof(int), stream);
    deg_count_kernel<<<dim3((E_ + 255) / 256, G_), 256, 0, stream>>>(dstA, deg_i);
    scan1_kernel<<<dim3(NBLK_, G_), 512, 0, stream>>>(deg_i, bsum);
    scan2_kernel<<<G_, 256, 0, stream>>>(bsum, bpre, off);
    scan3_kernel<<<dim3(NBLK_, G_), 512, 0, stream>>>(deg_i, bpre, off);
    scatter_kernel<<<dim3((E_ + 255) / 256, G_), 256, 0, stream>>>(
        srcA, dstA, ewA, ep, node_indices, off, deg_i, csr_src, csr_vsrc, csr_coef);

    // ---- per-graph-group GEMM + per-graph propagation ----
    for (int gbase = 0; gbase < G_; gbase += ng) {
        table_gemm_kernel<<<dim3(ng, (V_ + 127) / 128), 256, 0, stream>>>(
            emb, Wp + (size_t)gbase * D_ * H_, bp + (size_t)gbase * H_, P);

        for (int gi = 0; gi < ng; ++gi) {
            const int g = gbase + gi;
            const int*   idx   = node_indices + (size_t)g * N_;
            const int*   gid   = gidA + (size_t)g * N_;
            const int*   off_g = off + (size_t)g * (N_ + 1);
            const float* Pg    = P + (size_t)gi * V_ * H_;

            prop1_kernel<<<(N_ + 7) / 8, 256, 0, stream>>>(
                idx, off_g, csr_vsrc + (size_t)g * E_, csr_coef + (size_t)g * E_,
                Pg, hB);
            prop2_kernel<<<(N_ + 7) / 8, 256, 0, stream>>>(
                off_g, csr_src + (size_t)g * E_, csr_coef + (size_t)g * E_,
                hB, hA);

            doc_cls_kernel<<<B_, 128, 0, stream>>>(
                gid, hA, Wc + (size_t)g * H_ * C_, bc + (size_t)g * C_,
                logits + (size_t)g * B_ * C_);
        }
    }

    fuse_kernel<<<B_, 64, 0, stream>>>(logits, Wf, bf, out);
}